// Round 5
// baseline (1481.490 us; speedup 1.0000x reference)
//
#include <hip/hip_runtime.h>
#include <hip/hip_bf16.h>
#include <cstdint>

#define N_PROT 19000
#define N_DRUGS 4200
#define BATCH 8192
#define D0 1024
#define D1 512
#define D2 128
#define NROWS (2 * BATCH)  // 16384 MLP rows, interleaved: r = 2*i + s
#define MAXNNZ 192         // Binomial(19000,0.002): mean 38, sd 6.2 — >20 sigma
#define BR 64              // rows per fused block -> 256 blocks = 1/CU
#define BK1 64             // K-chunk for phase-1 staging
#define NCHUNK 8           // gather column chunks (one per XCD)
#define CCOLS (D0 / NCHUNK)

// DIAGNOSTIC repetition factors: make each kernel's dispatch > ~200 us so it
// surfaces above the harness's 1.25GB fill (~190 us) in rocprof top-5.
// All kernel bodies are idempotent; reps are race-checked. Revert next round.
#define REP_CONV 12
#define REP_SCAN 5
#define REP_GATH 20
#define REP_FUSE 16

typedef __bf16 bf16_t;
typedef __bf16 bf16x8 __attribute__((ext_vector_type(8)));
typedef __bf16 bf16x4 __attribute__((ext_vector_type(4)));
typedef __bf16 bf16x2 __attribute__((ext_vector_type(2)));
typedef float f32x4 __attribute__((ext_vector_type(4)));
typedef float f32x8 __attribute__((ext_vector_type(8)));

// ---------------------------------------------------------------------------
// Kernel 1: weight conversions. W0->W0b bf16; W1->W1T bf16; W2->W2T bf16.
// Grid-stride with unroll-4 (4 independent 16B loads in flight).
// ---------------------------------------------------------------------------
__global__ __launch_bounds__(256) void k_convert(
    const float* __restrict__ W0, const float* __restrict__ W1,
    const float* __restrict__ W2, bf16_t* __restrict__ W0b,
    bf16_t* __restrict__ W1T, bf16_t* __restrict__ W2T)
{
  const int S = gridDim.x * 256;
  const int tid0 = blockIdx.x * 256 + threadIdx.x;
  constexpr int NV0 = N_PROT * D0 / 4;  // 4,864,000 float4 groups

  for (int rep = 0; rep < REP_CONV; ++rep) {
    int v = tid0;
    for (; v + 3 * S < NV0; v += 4 * S) {
      f32x4 w0 = reinterpret_cast<const f32x4*>(W0)[v];
      f32x4 w1 = reinterpret_cast<const f32x4*>(W0)[v + S];
      f32x4 w2 = reinterpret_cast<const f32x4*>(W0)[v + 2 * S];
      f32x4 w3 = reinterpret_cast<const f32x4*>(W0)[v + 3 * S];
      bf16x4 o0 = {(bf16_t)w0[0], (bf16_t)w0[1], (bf16_t)w0[2], (bf16_t)w0[3]};
      bf16x4 o1 = {(bf16_t)w1[0], (bf16_t)w1[1], (bf16_t)w1[2], (bf16_t)w1[3]};
      bf16x4 o2 = {(bf16_t)w2[0], (bf16_t)w2[1], (bf16_t)w2[2], (bf16_t)w2[3]};
      bf16x4 o3 = {(bf16_t)w3[0], (bf16_t)w3[1], (bf16_t)w3[2], (bf16_t)w3[3]};
      reinterpret_cast<bf16x4*>(W0b)[v] = o0;
      reinterpret_cast<bf16x4*>(W0b)[v + S] = o1;
      reinterpret_cast<bf16x4*>(W0b)[v + 2 * S] = o2;
      reinterpret_cast<bf16x4*>(W0b)[v + 3 * S] = o3;
    }
    for (; v < NV0; v += S) {
      f32x4 w = reinterpret_cast<const f32x4*>(W0)[v];
      bf16x4 o = {(bf16_t)w[0], (bf16_t)w[1], (bf16_t)w[2], (bf16_t)w[3]};
      reinterpret_cast<bf16x4*>(W0b)[v] = o;
    }
    for (int idx = tid0; idx < D0 * D1; idx += S) {   // idx = n*D0 + k
      const int n = idx >> 10, k = idx & (D0 - 1);
      W1T[idx] = (bf16_t)W1[(size_t)k * D1 + n];
    }
    for (int idx = tid0; idx < D1 * D2; idx += S) {   // idx = n*D1 + k
      const int n = idx >> 9, k = idx & (D1 - 1);
      W2T[idx] = (bf16_t)W2[(size_t)k * D2 + n];
    }
  }
}

// ---------------------------------------------------------------------------
// Kernel 2: scan table rows -> per-drug nonzero index lists.
// Unroll-8: 8 independent uint4 loads in flight per thread (Little's-law fix
// for the latency-bound behavior seen in round 1).
// ---------------------------------------------------------------------------
__global__ __launch_bounds__(256) void k_scan(
    const uint32_t* __restrict__ table_u, int* __restrict__ g_cnt,
    int* __restrict__ g_idx)
{
  __shared__ int s_idx[MAXNNZ];
  __shared__ int s_cnt;
  const int d = blockIdx.x;
  const uint4* row = reinterpret_cast<const uint4*>(table_u + (size_t)d * N_PROT);
  constexpr int NQ = N_PROT / 4;  // 4750

#define SCAN_BODY(v, qq)                                                        \
  if ((v).x | (v).y | (v).z | (v).w) {                                          \
    if ((v).x) { int k = atomicAdd(&s_cnt, 1); if (k < MAXNNZ) s_idx[k] = 4 * (qq) + 0; } \
    if ((v).y) { int k = atomicAdd(&s_cnt, 1); if (k < MAXNNZ) s_idx[k] = 4 * (qq) + 1; } \
    if ((v).z) { int k = atomicAdd(&s_cnt, 1); if (k < MAXNNZ) s_idx[k] = 4 * (qq) + 2; } \
    if ((v).w) { int k = atomicAdd(&s_cnt, 1); if (k < MAXNNZ) s_idx[k] = 4 * (qq) + 3; } \
  }

  for (int rep = 0; rep < REP_SCAN; ++rep) {
    __syncthreads();                    // all waves done reading s_cnt (prev rep)
    if (threadIdx.x == 0) s_cnt = 0;
    __syncthreads();

    int q = threadIdx.x;
#pragma unroll
    for (int r = 0; r < 2; ++r) {       // 2 x 8 strides of 256 -> q_base 0..4095
      uint4 v[8];
#pragma unroll
      for (int u = 0; u < 8; ++u) v[u] = row[q + u * 256];
#pragma unroll
      for (int u = 0; u < 8; ++u) { SCAN_BODY(v[u], q + u * 256) }
      q += 2048;
    }
    {                                   // strides 16,17 -> 4096..4607
      uint4 v0 = row[q];
      uint4 v1 = row[q + 256];
      SCAN_BODY(v0, q)
      SCAN_BODY(v1, q + 256)
      q += 512;
    }
    if (q < NQ) {                       // 4608..4749 (threads 0..141)
      uint4 v = row[q];
      SCAN_BODY(v, q)
    }

    __syncthreads();
    const int n = min(s_cnt, MAXNNZ);
    if (threadIdx.x == 0) g_cnt[d] = n;
    for (int t = threadIdx.x; t < n; t += 256) g_idx[(size_t)d * MAXNNZ + t] = s_idx[t];
  }
#undef SCAN_BODY
}

// ---------------------------------------------------------------------------
// Kernel 3: XCD-chunked gather. h0[d][:] = sum of listed W0b rows + b0.
// chunk = blockIdx % 8 == XCD (round-robin dispatch) pins each 128-col strip
// (4.86 MB) mostly in one XCD's L2. Unroll-4.
// ---------------------------------------------------------------------------
__global__ __launch_bounds__(64) void k_gather(
    const bf16_t* __restrict__ W0b, const int* __restrict__ g_cnt,
    const int* __restrict__ g_idx, const float* __restrict__ b0,
    float* __restrict__ h0)
{
  __shared__ int s_idx[MAXNNZ];
  const int chunk = blockIdx.x & (NCHUNK - 1);
  const int d = blockIdx.x >> 3;
  const int n = g_cnt[d];
  for (int t = threadIdx.x; t < n; t += 64) s_idx[t] = g_idx[(size_t)d * MAXNNZ + t];
  __syncthreads();

  const int col = chunk * CCOLS + threadIdx.x * 2;
  const float bb0 = b0[col], bb1 = b0[col + 1];

  for (int rep = 0; rep < REP_GATH; ++rep) {
    float c0 = 0.f, c1 = 0.f, d0_ = 0.f, d1_ = 0.f;
    float e0 = 0.f, e1 = 0.f, f0 = 0.f, f1 = 0.f;
    int t = 0;
    for (; t + 4 <= n; t += 4) {
      bf16x2 w0 = *reinterpret_cast<const bf16x2*>(W0b + (size_t)s_idx[t] * D0 + col);
      bf16x2 w1 = *reinterpret_cast<const bf16x2*>(W0b + (size_t)s_idx[t + 1] * D0 + col);
      bf16x2 w2 = *reinterpret_cast<const bf16x2*>(W0b + (size_t)s_idx[t + 2] * D0 + col);
      bf16x2 w3 = *reinterpret_cast<const bf16x2*>(W0b + (size_t)s_idx[t + 3] * D0 + col);
      c0 += (float)w0[0]; c1 += (float)w0[1];
      d0_ += (float)w1[0]; d1_ += (float)w1[1];
      e0 += (float)w2[0]; e1 += (float)w2[1];
      f0 += (float)w3[0]; f1 += (float)w3[1];
    }
    for (; t < n; ++t) {
      bf16x2 w = *reinterpret_cast<const bf16x2*>(W0b + (size_t)s_idx[t] * D0 + col);
      c0 += (float)w[0]; c1 += (float)w[1];
    }
    float2 o;
    o.x = ((c0 + d0_) + (e0 + f0)) + bb0;
    o.y = ((c1 + d1_) + (e1 + f1)) + bb1;
    *reinterpret_cast<float2*>(h0 + (size_t)d * D0 + col) = o;
  }
}

// ---------------------------------------------------------------------------
// Kernel 4: FUSED build_H + gemm1(relu) + gemm2 + pair-dot.
// Change vs round 4: prefetch loads issued AFTER __syncthreads (the compiler's
// vmcnt(0)-drain before s_barrier no longer serializes them; they now fly
// under the 32-MFMA compute block).
// ---------------------------------------------------------------------------
__global__ __launch_bounds__(512, 2) void k_fused(
    const float* __restrict__ h0, const int* __restrict__ pairs,
    const float* __restrict__ conc, const float* __restrict__ W0last,
    const float* __restrict__ b1v, const bf16_t* __restrict__ W1T,
    const float* __restrict__ b2v, const bf16_t* __restrict__ W2T,
    float* __restrict__ out)
{
  __shared__ bf16_t smemA[2][BR * BK1];   // 2 x 8 KB
  __shared__ bf16_t smemH1[BR * D1];      // 64 KB
  __shared__ float red[8][32];

  const int tid = threadIdx.x;
  const int w = tid >> 6;        // wave 0..7
  const int lane = tid & 63;
  const int fr = lane & 15;
  const int q = lane >> 4;       // 0..3
  const int fk8 = q * 8;
  const int row0 = blockIdx.x * BR;

  // --- staging role: thread covers (srow, k8-slot) ---
  const int srow = tid >> 3;          // 0..63
  const int sk8 = (tid & 7) * 8;      // 0..56
  const int gr = row0 + srow;
  const int drug = pairs[gr];
  const float c = conc[3 * (gr >> 1) + 1 + (gr & 1)];
  const float* hrow = h0 + (size_t)drug * D0;
  const uint32_t sbyte = srow * 128 + ((sk8 * 2) ^ ((srow & 7) << 4));

  for (int rep = 0; rep < REP_FUSE; ++rep) {
    f32x8 hA, hB, wlA, wlB;
    bf16x8 bA[8], bB[8];
    f32x4 acc[4][4] = {};

    auto loadH = [&](int t, f32x8& h, f32x8& wl) {
      h = *reinterpret_cast<const f32x8*>(hrow + t * BK1 + sk8);
      wl = *reinterpret_cast<const f32x8*>(W0last + t * BK1 + sk8);
    };
    auto loadB = [&](int t, bf16x8* dst) {
#pragma unroll
      for (int n = 0; n < 4; ++n)
#pragma unroll
        for (int kk = 0; kk < 2; ++kk)
          dst[n * 2 + kk] = *reinterpret_cast<const bf16x8*>(
              W1T + (size_t)(w * 64 + n * 16 + fr) * D0 + t * BK1 + kk * 32 + fk8);
    };
    auto stage = [&](int buf, const f32x8& h, const f32x8& wl) {
      bf16x8 o;
#pragma unroll
      for (int j = 0; j < 8; ++j) o[j] = (bf16_t)fmaxf(h[j] + c * wl[j], 0.f);
      *reinterpret_cast<bf16x8*>((char*)&smemA[buf][0] + sbyte) = o;
    };
    auto compute = [&](int buf, const bf16x8* b) {
#pragma unroll
      for (int kk = 0; kk < 2; ++kk) {
        bf16x8 a[4];
#pragma unroll
        for (int m = 0; m < 4; ++m) {
          const int row = m * 16 + fr;
          const uint32_t byte = row * 128 + ((uint32_t)(kk * 64 + q * 16) ^ ((row & 7) << 4));
          a[m] = *reinterpret_cast<const bf16x8*>((const char*)&smemA[buf][0] + byte);
        }
#pragma unroll
        for (int m = 0; m < 4; ++m)
#pragma unroll
          for (int n = 0; n < 4; ++n)
            acc[m][n] = __builtin_amdgcn_mfma_f32_16x16x32_bf16(a[m], b[n * 2 + kk], acc[m][n], 0, 0, 0);
      }
    };

    // --- phase 1: K1 = 1024 in 16 chunks; loads AFTER the barrier ---
    loadH(0, hA, wlA);
    loadB(0, bA);
    for (int t = 0; t < 16; t += 2) {
      stage(0, hA, wlA);
      __syncthreads();
      if (t + 1 < 16) { loadH(t + 1, hB, wlB); loadB(t + 1, bB); }
      compute(0, bA);

      stage(1, hB, wlB);
      __syncthreads();
      if (t + 2 < 16) { loadH(t + 2, hA, wlA); loadB(t + 2, bA); }
      compute(1, bB);
    }

    // --- phase-1 epilogue: relu(acc + b1) -> bf16 H1 tile in LDS (swizzled) ---
#pragma unroll
    for (int m = 0; m < 4; ++m)
#pragma unroll
      for (int n = 0; n < 4; ++n) {
        const int col = w * 64 + n * 16 + fr;
        const float bb = b1v[col];
#pragma unroll
        for (int r = 0; r < 4; ++r) {
          const int row = m * 16 + 4 * q + r;
          const float v = fmaxf(acc[m][n][r] + bb, 0.f);
          const uint32_t byte = row * 1024 + ((uint32_t)(col * 2) ^ ((row & 7) << 4));
          *reinterpret_cast<bf16_t*>((char*)smemH1 + byte) = (bf16_t)v;
        }
      }
    __syncthreads();

    // --- phase 2: layer-2 gemm, wave w -> out cols w*16..w*16+15 ---
    f32x4 acc2[4] = {};
#pragma unroll 2
    for (int kk = 0; kk < 16; ++kk) {
      const bf16x8 b2 = *reinterpret_cast<const bf16x8*>(
          W2T + (size_t)(w * 16 + fr) * D1 + kk * 32 + fk8);
      bf16x8 a2[4];
#pragma unroll
      for (int m = 0; m < 4; ++m) {
        const int row = m * 16 + fr;
        const uint32_t byte = row * 1024 + ((uint32_t)(kk * 64 + q * 16) ^ ((row & 7) << 4));
        a2[m] = *reinterpret_cast<const bf16x8*>((const char*)smemH1 + byte);
      }
#pragma unroll
      for (int m = 0; m < 4; ++m)
        acc2[m] = __builtin_amdgcn_mfma_f32_16x16x32_bf16(a2[m], b2, acc2[m], 0, 0, 0);
    }

    // --- pair-dot epilogue ---
    const float bb2 = b2v[w * 16 + fr];
#pragma unroll
    for (int m = 0; m < 4; ++m) {
      const float v0 = acc2[m][0] + bb2;
      const float v1 = acc2[m][1] + bb2;
      const float v2 = acc2[m][2] + bb2;
      const float v3 = acc2[m][3] + bb2;
      float pa = v0 * v1, pb = v2 * v3;
#pragma unroll
      for (int off = 8; off >= 1; off >>= 1) {
        pa += __shfl_xor(pa, off);
        pb += __shfl_xor(pb, off);
      }
      if (fr == 0) {
        red[w][m * 8 + 2 * q] = pa;
        red[w][m * 8 + 2 * q + 1] = pb;
      }
    }
    __syncthreads();
    if (tid < 32) {
      float s = 0.f;
#pragma unroll
      for (int ww = 0; ww < 8; ++ww) s += red[ww][tid];
      out[blockIdx.x * 32 + tid] = s;
    }
  }
}

extern "C" void kernel_launch(void* const* d_in, const int* in_sizes, int n_in,
                              void* d_out, int out_size, void* d_ws, size_t ws_size,
                              hipStream_t stream) {
  const float* table = (const float*)d_in[0];
  const int*   pairs = (const int*)d_in[1];
  const float* conc  = (const float*)d_in[2];
  const float* W0    = (const float*)d_in[3];
  const float* b0    = (const float*)d_in[4];
  const float* W1    = (const float*)d_in[5];
  const float* b1    = (const float*)d_in[6];
  const float* W2    = (const float*)d_in[7];
  const float* b2    = (const float*)d_in[8];
  float* out = (float*)d_out;

  // Workspace (16B-aligned, ~60.5 MB):
  char* ws = (char*)d_ws;
  float*  h0  = (float*)ws;  ws += (size_t)N_DRUGS * D0 * sizeof(float);    // 17.2 MB
  bf16_t* W0b = (bf16_t*)ws; ws += (size_t)N_PROT * D0 * sizeof(bf16_t);    // 38.9 MB
  bf16_t* W1T = (bf16_t*)ws; ws += (size_t)D1 * D0 * sizeof(bf16_t);        //  1.0 MB
  bf16_t* W2T = (bf16_t*)ws; ws += (size_t)D2 * D1 * sizeof(bf16_t);        //  0.13 MB
  int* g_idx = (int*)ws;     ws += (size_t)N_DRUGS * MAXNNZ * sizeof(int);  //  3.2 MB
  int* g_cnt = (int*)ws;     ws += (size_t)N_DRUGS * sizeof(int);           // 16.8 KB

  k_convert<<<2048, 256, 0, stream>>>(W0, W1, W2, W0b, W1T, W2T);
  k_scan<<<N_DRUGS, 256, 0, stream>>>((const uint32_t*)table, g_cnt, g_idx);
  k_gather<<<N_DRUGS * NCHUNK, 64, 0, stream>>>(W0b, g_cnt, g_idx, b0, h0);
  k_fused<<<NROWS / BR, 512, 0, stream>>>(h0, pairs, conc, W0 + (size_t)N_PROT * D0,
                                          b1, W1T, b2, W2T, out);
}

// Round 6
// 191.702 us; speedup vs baseline: 7.7281x; 7.7281x over previous
//
#include <hip/hip_runtime.h>
#include <hip/hip_bf16.h>
#include <cstdint>

#define N_PROT 19000
#define N_DRUGS 4200
#define BATCH 8192
#define D0 1024
#define D1 512
#define D2 128
#define NROWS (2 * BATCH)  // 16384 MLP rows, interleaved: r = 2*i + s
#define MAXNNZ 192         // Binomial(19000,0.002): mean 38, sd 6.2 — >20 sigma
#define BR 32              // rows per fused block: LDS 41KB -> 2 blocks/CU resident
#define BK1 64             // K-chunk for phase-1 staging
#define NCHUNK 8           // gather column chunks (one per XCD)
#define CCOLS (D0 / NCHUNK)

typedef __bf16 bf16_t;
typedef __bf16 bf16x8 __attribute__((ext_vector_type(8)));
typedef __bf16 bf16x4 __attribute__((ext_vector_type(4)));
typedef __bf16 bf16x2 __attribute__((ext_vector_type(2)));
typedef float f32x4 __attribute__((ext_vector_type(4)));

// ---------------------------------------------------------------------------
// Kernel 1: weight conversions. W0->W0b bf16; W1->W1T bf16; W2->W2T bf16.
// ---------------------------------------------------------------------------
__global__ __launch_bounds__(256) void k_convert(
    const float* __restrict__ W0, const float* __restrict__ W1,
    const float* __restrict__ W2, bf16_t* __restrict__ W0b,
    bf16_t* __restrict__ W1T, bf16_t* __restrict__ W2T)
{
  const int S = gridDim.x * 256;
  const int tid0 = blockIdx.x * 256 + threadIdx.x;
  constexpr int NV0 = N_PROT * D0 / 4;  // 4,864,000 float4 groups

  int v = tid0;
  for (; v + 3 * S < NV0; v += 4 * S) {
    f32x4 w0 = reinterpret_cast<const f32x4*>(W0)[v];
    f32x4 w1 = reinterpret_cast<const f32x4*>(W0)[v + S];
    f32x4 w2 = reinterpret_cast<const f32x4*>(W0)[v + 2 * S];
    f32x4 w3 = reinterpret_cast<const f32x4*>(W0)[v + 3 * S];
    bf16x4 o0 = {(bf16_t)w0[0], (bf16_t)w0[1], (bf16_t)w0[2], (bf16_t)w0[3]};
    bf16x4 o1 = {(bf16_t)w1[0], (bf16_t)w1[1], (bf16_t)w1[2], (bf16_t)w1[3]};
    bf16x4 o2 = {(bf16_t)w2[0], (bf16_t)w2[1], (bf16_t)w2[2], (bf16_t)w2[3]};
    bf16x4 o3 = {(bf16_t)w3[0], (bf16_t)w3[1], (bf16_t)w3[2], (bf16_t)w3[3]};
    reinterpret_cast<bf16x4*>(W0b)[v] = o0;
    reinterpret_cast<bf16x4*>(W0b)[v + S] = o1;
    reinterpret_cast<bf16x4*>(W0b)[v + 2 * S] = o2;
    reinterpret_cast<bf16x4*>(W0b)[v + 3 * S] = o3;
  }
  for (; v < NV0; v += S) {
    f32x4 w = reinterpret_cast<const f32x4*>(W0)[v];
    bf16x4 o = {(bf16_t)w[0], (bf16_t)w[1], (bf16_t)w[2], (bf16_t)w[3]};
    reinterpret_cast<bf16x4*>(W0b)[v] = o;
  }
  for (int idx = tid0; idx < D0 * D1; idx += S) {   // idx = n*D0 + k
    const int n = idx >> 10, k = idx & (D0 - 1);
    W1T[idx] = (bf16_t)W1[(size_t)k * D1 + n];
  }
  for (int idx = tid0; idx < D1 * D2; idx += S) {   // idx = n*D1 + k
    const int n = idx >> 9, k = idx & (D1 - 1);
    W2T[idx] = (bf16_t)W2[(size_t)k * D2 + n];
  }
}

// ---------------------------------------------------------------------------
// Kernel 2: scan table rows -> per-drug nonzero index lists. Unroll-8.
// ---------------------------------------------------------------------------
__global__ __launch_bounds__(256) void k_scan(
    const uint32_t* __restrict__ table_u, int* __restrict__ g_cnt,
    int* __restrict__ g_idx)
{
  __shared__ int s_idx[MAXNNZ];
  __shared__ int s_cnt;
  const int d = blockIdx.x;
  if (threadIdx.x == 0) s_cnt = 0;
  __syncthreads();
  const uint4* row = reinterpret_cast<const uint4*>(table_u + (size_t)d * N_PROT);
  constexpr int NQ = N_PROT / 4;  // 4750

#define SCAN_BODY(v, qq)                                                        \
  if ((v).x | (v).y | (v).z | (v).w) {                                          \
    if ((v).x) { int k = atomicAdd(&s_cnt, 1); if (k < MAXNNZ) s_idx[k] = 4 * (qq) + 0; } \
    if ((v).y) { int k = atomicAdd(&s_cnt, 1); if (k < MAXNNZ) s_idx[k] = 4 * (qq) + 1; } \
    if ((v).z) { int k = atomicAdd(&s_cnt, 1); if (k < MAXNNZ) s_idx[k] = 4 * (qq) + 2; } \
    if ((v).w) { int k = atomicAdd(&s_cnt, 1); if (k < MAXNNZ) s_idx[k] = 4 * (qq) + 3; } \
  }

  int q = threadIdx.x;
#pragma unroll
  for (int r = 0; r < 2; ++r) {       // q_base 0..4095
    uint4 v[8];
#pragma unroll
    for (int u = 0; u < 8; ++u) v[u] = row[q + u * 256];
#pragma unroll
    for (int u = 0; u < 8; ++u) { SCAN_BODY(v[u], q + u * 256) }
    q += 2048;
  }
  {                                   // 4096..4607
    uint4 v0 = row[q];
    uint4 v1 = row[q + 256];
    SCAN_BODY(v0, q)
    SCAN_BODY(v1, q + 256)
    q += 512;
  }
  if (q < NQ) {                       // 4608..4749 (threads 0..141)
    uint4 v = row[q];
    SCAN_BODY(v, q)
  }
#undef SCAN_BODY

  __syncthreads();
  const int n = min(s_cnt, MAXNNZ);
  if (threadIdx.x == 0) g_cnt[d] = n;
  for (int t = threadIdx.x; t < n; t += 256) g_idx[(size_t)d * MAXNNZ + t] = s_idx[t];
}

// ---------------------------------------------------------------------------
// Kernel 3: XCD-chunked gather. h0[d][:] = sum of listed W0b rows + b0.
// chunk = blockIdx % 8 == XCD pins each 128-col strip (4.86 MB) in one L2.
// ---------------------------------------------------------------------------
__global__ __launch_bounds__(64) void k_gather(
    const bf16_t* __restrict__ W0b, const int* __restrict__ g_cnt,
    const int* __restrict__ g_idx, const float* __restrict__ b0,
    float* __restrict__ h0)
{
  __shared__ int s_idx[MAXNNZ];
  const int chunk = blockIdx.x & (NCHUNK - 1);
  const int d = blockIdx.x >> 3;
  const int n = g_cnt[d];
  for (int t = threadIdx.x; t < n; t += 64) s_idx[t] = g_idx[(size_t)d * MAXNNZ + t];
  __syncthreads();

  const int col = chunk * CCOLS + threadIdx.x * 2;
  float c0 = 0.f, c1 = 0.f, d0_ = 0.f, d1_ = 0.f;
  float e0 = 0.f, e1 = 0.f, f0 = 0.f, f1 = 0.f;
  int t = 0;
  for (; t + 4 <= n; t += 4) {
    bf16x2 w0 = *reinterpret_cast<const bf16x2*>(W0b + (size_t)s_idx[t] * D0 + col);
    bf16x2 w1 = *reinterpret_cast<const bf16x2*>(W0b + (size_t)s_idx[t + 1] * D0 + col);
    bf16x2 w2 = *reinterpret_cast<const bf16x2*>(W0b + (size_t)s_idx[t + 2] * D0 + col);
    bf16x2 w3 = *reinterpret_cast<const bf16x2*>(W0b + (size_t)s_idx[t + 3] * D0 + col);
    c0 += (float)w0[0]; c1 += (float)w0[1];
    d0_ += (float)w1[0]; d1_ += (float)w1[1];
    e0 += (float)w2[0]; e1 += (float)w2[1];
    f0 += (float)w3[0]; f1 += (float)w3[1];
  }
  for (; t < n; ++t) {
    bf16x2 w = *reinterpret_cast<const bf16x2*>(W0b + (size_t)s_idx[t] * D0 + col);
    c0 += (float)w[0]; c1 += (float)w[1];
  }
  float2 o;
  o.x = ((c0 + d0_) + (e0 + f0)) + b0[col];
  o.y = ((c1 + d1_) + (e1 + f1)) + b0[col + 1];
  *reinterpret_cast<float2*>(h0 + (size_t)d * D0 + col) = o;
}

// ---------------------------------------------------------------------------
// Kernel 4: FUSED build_H + gemm1(relu) + gemm2 + pair-dot.
// BR=32, 512 thr (8 waves x 64-col strips of layer-1), LDS ~41KB:
//   smemA 2x[32][64] bf16 (8KB dbuf) + smemH1 [32][512] bf16 (32KB) + red.
// -> 2 blocks/CU co-resident (grid 512 = 2/CU): cross-block TLP hides the
// per-chunk barrier drain that serialized the BR=64 version (24% occ, 14% mfma).
// C/D mapping: lane l, reg r -> row = m*16 + 4*(l>>4) + r, col = l&15.
// Swizzle: byte ^= (row&7)<<4 on both sides (16B granule).
// ---------------------------------------------------------------------------
__global__ __launch_bounds__(512, 4) void k_fused(
    const float* __restrict__ h0, const int* __restrict__ pairs,
    const float* __restrict__ conc, const float* __restrict__ W0last,
    const float* __restrict__ b1v, const bf16_t* __restrict__ W1T,
    const float* __restrict__ b2v, const bf16_t* __restrict__ W2T,
    float* __restrict__ out)
{
  __shared__ bf16_t smemA[2][BR * BK1];   // 2 x 4 KB
  __shared__ bf16_t smemH1[BR * D1];      // 32 KB
  __shared__ float red[8][16];

  const int tid = threadIdx.x;
  const int w = tid >> 6;        // wave 0..7
  const int lane = tid & 63;
  const int fr = lane & 15;
  const int q = lane >> 4;       // 0..3
  const int fk8 = q * 8;
  const int row0 = blockIdx.x * BR;

  // --- staging role: thread covers (srow, 4-float k-slot) ---
  const int srow = tid >> 4;          // 0..31
  const int sk4 = (tid & 15) * 4;     // 0..60
  const int gr = row0 + srow;
  const int drug = pairs[gr];
  const float c = conc[3 * (gr >> 1) + 1 + (gr & 1)];
  const float* hrow = h0 + (size_t)drug * D0;
  const uint32_t sbyte = srow * 128 + ((uint32_t)(sk4 * 2) ^ ((srow & 7) << 4));

  f32x4 hA, hB, wlA, wlB;
  bf16x8 bA[8], bB[8];
  f32x4 acc[2][4] = {};

  auto loadH = [&](int t, f32x4& h, f32x4& wl) {
    h = *reinterpret_cast<const f32x4*>(hrow + t * BK1 + sk4);
    wl = *reinterpret_cast<const f32x4*>(W0last + t * BK1 + sk4);
  };
  auto loadB = [&](int t, bf16x8* dst) {
#pragma unroll
    for (int n = 0; n < 4; ++n)
#pragma unroll
      for (int kk = 0; kk < 2; ++kk)
        dst[n * 2 + kk] = *reinterpret_cast<const bf16x8*>(
            W1T + (size_t)(w * 64 + n * 16 + fr) * D0 + t * BK1 + kk * 32 + fk8);
  };
  auto stage = [&](int buf, const f32x4& h, const f32x4& wl) {
    bf16x4 o;
#pragma unroll
    for (int j = 0; j < 4; ++j) o[j] = (bf16_t)fmaxf(h[j] + c * wl[j], 0.f);
    *reinterpret_cast<bf16x4*>((char*)&smemA[buf][0] + sbyte) = o;
  };
  auto compute = [&](int buf, const bf16x8* b) {
#pragma unroll
    for (int kk = 0; kk < 2; ++kk) {
      bf16x8 a[2];
#pragma unroll
      for (int m = 0; m < 2; ++m) {
        const int row = m * 16 + fr;
        const uint32_t byte = row * 128 + ((uint32_t)(kk * 64 + q * 16) ^ ((row & 7) << 4));
        a[m] = *reinterpret_cast<const bf16x8*>((const char*)&smemA[buf][0] + byte);
      }
#pragma unroll
      for (int m = 0; m < 2; ++m)
#pragma unroll
        for (int n = 0; n < 4; ++n)
          acc[m][n] = __builtin_amdgcn_mfma_f32_16x16x32_bf16(a[m], b[n * 2 + kk], acc[m][n], 0, 0, 0);
    }
  };

  // --- phase 1: K1 = 1024 in 16 chunks; prefetch issued AFTER the barrier ---
  loadH(0, hA, wlA);
  loadB(0, bA);
  for (int t = 0; t < 16; t += 2) {
    stage(0, hA, wlA);
    __syncthreads();
    if (t + 1 < 16) { loadH(t + 1, hB, wlB); loadB(t + 1, bB); }
    compute(0, bA);

    stage(1, hB, wlB);
    __syncthreads();
    if (t + 2 < 16) { loadH(t + 2, hA, wlA); loadB(t + 2, bA); }
    compute(1, bB);
  }

  // --- phase-1 epilogue: relu(acc + b1) -> bf16 H1 tile in LDS (swizzled) ---
#pragma unroll
  for (int m = 0; m < 2; ++m)
#pragma unroll
    for (int n = 0; n < 4; ++n) {
      const int col = w * 64 + n * 16 + fr;
      const float bb = b1v[col];
#pragma unroll
      for (int r = 0; r < 4; ++r) {
        const int row = m * 16 + 4 * q + r;
        const float v = fmaxf(acc[m][n][r] + bb, 0.f);
        const uint32_t byte = row * 1024 + ((uint32_t)(col * 2) ^ ((row & 7) << 4));
        *reinterpret_cast<bf16_t*>((char*)smemH1 + byte) = (bf16_t)v;
      }
    }
  __syncthreads();

  // --- phase 2: layer-2 gemm, wave w -> out cols w*16..w*16+15 ---
  f32x4 acc2[2] = {};
#pragma unroll 2
  for (int kk = 0; kk < 16; ++kk) {
    const bf16x8 b2 = *reinterpret_cast<const bf16x8*>(
        W2T + (size_t)(w * 16 + fr) * D1 + kk * 32 + fk8);
    bf16x8 a2[2];
#pragma unroll
    for (int m = 0; m < 2; ++m) {
      const int row = m * 16 + fr;
      const uint32_t byte = row * 1024 + ((uint32_t)(kk * 64 + q * 16) ^ ((row & 7) << 4));
      a2[m] = *reinterpret_cast<const bf16x8*>((const char*)smemH1 + byte);
    }
#pragma unroll
    for (int m = 0; m < 2; ++m)
      acc2[m] = __builtin_amdgcn_mfma_f32_16x16x32_bf16(a2[m], b2, acc2[m], 0, 0, 0);
  }

  // --- pair-dot epilogue: rows 4q+r within each 16-row m-tile are pairs ---
  const float bb2 = b2v[w * 16 + fr];
#pragma unroll
  for (int m = 0; m < 2; ++m) {
    const float v0 = acc2[m][0] + bb2;
    const float v1 = acc2[m][1] + bb2;
    const float v2 = acc2[m][2] + bb2;
    const float v3 = acc2[m][3] + bb2;
    float pa = v0 * v1, pb = v2 * v3;
#pragma unroll
    for (int off = 8; off >= 1; off >>= 1) {
      pa += __shfl_xor(pa, off);
      pb += __shfl_xor(pb, off);
    }
    if (fr == 0) {
      red[w][m * 8 + 2 * q] = pa;
      red[w][m * 8 + 2 * q + 1] = pb;
    }
  }
  __syncthreads();
  if (tid < 16) {
    float s = 0.f;
#pragma unroll
    for (int ww = 0; ww < 8; ++ww) s += red[ww][tid];
    out[blockIdx.x * 16 + tid] = s;
  }
}

extern "C" void kernel_launch(void* const* d_in, const int* in_sizes, int n_in,
                              void* d_out, int out_size, void* d_ws, size_t ws_size,
                              hipStream_t stream) {
  const float* table = (const float*)d_in[0];
  const int*   pairs = (const int*)d_in[1];
  const float* conc  = (const float*)d_in[2];
  const float* W0    = (const float*)d_in[3];
  const float* b0    = (const float*)d_in[4];
  const float* W1    = (const float*)d_in[5];
  const float* b1    = (const float*)d_in[6];
  const float* W2    = (const float*)d_in[7];
  const float* b2    = (const float*)d_in[8];
  float* out = (float*)d_out;

  // Workspace (16B-aligned, ~60.5 MB):
  char* ws = (char*)d_ws;
  float*  h0  = (float*)ws;  ws += (size_t)N_DRUGS * D0 * sizeof(float);    // 17.2 MB
  bf16_t* W0b = (bf16_t*)ws; ws += (size_t)N_PROT * D0 * sizeof(bf16_t);    // 38.9 MB
  bf16_t* W1T = (bf16_t*)ws; ws += (size_t)D1 * D0 * sizeof(bf16_t);        //  1.0 MB
  bf16_t* W2T = (bf16_t*)ws; ws += (size_t)D2 * D1 * sizeof(bf16_t);        //  0.13 MB
  int* g_idx = (int*)ws;     ws += (size_t)N_DRUGS * MAXNNZ * sizeof(int);  //  3.2 MB
  int* g_cnt = (int*)ws;     ws += (size_t)N_DRUGS * sizeof(int);           // 16.8 KB

  k_convert<<<2048, 256, 0, stream>>>(W0, W1, W2, W0b, W1T, W2T);
  k_scan<<<N_DRUGS, 256, 0, stream>>>((const uint32_t*)table, g_cnt, g_idx);
  k_gather<<<N_DRUGS * NCHUNK, 64, 0, stream>>>(W0b, g_cnt, g_idx, b0, h0);
  k_fused<<<NROWS / BR, 512, 0, stream>>>(h0, pairs, conc, W0 + (size_t)N_PROT * D0,
                                          b1, W1T, b2, W2T, out);
}